// Round 2
// baseline (197.698 us; speedup 1.0000x reference)
//
#include <hip/hip_runtime.h>
#include <hip/hip_bf16.h>

typedef __attribute__((ext_vector_type(4))) float f32x4;
typedef __attribute__((ext_vector_type(8))) short bf16x8;

// global -> LDS direct DMA, 16 B/lane. LDS dest = wave-uniform base + lane*16.
#define GLDS16(gp, lp) __builtin_amdgcn_global_load_lds( \
    (__attribute__((address_space(1))) void*)(void*)(gp), \
    (__attribute__((address_space(3))) void*)(lp), 16, 0, 0)

static constexpr int Mtot = 4 * 24 * 512;   // 49152 rows (b,h,n)
static constexpr int Ktot = 128 * 6;        // 768 = (C+8) features x (silu + 5 RBF)
static constexpr int Otot = 512;
static constexpr int Hh   = 24;

__device__ inline unsigned short f2bf(float f) {
    __hip_bfloat16 h = __float2bfloat16(f);
    unsigned short u;
    __builtin_memcpy(&u, &h, 2);
    return u;
}

// 6 features (silu + 5 RBF at grid -1,-.5,0,.5,1; inv_h=2) packed into 3 dwords
__device__ inline void feat6(float v, unsigned* o) {
    float f0 = v / (1.0f + __expf(-v));
    float r[5];
    #pragma unroll
    for (int g = 0; g < 5; ++g) {
        float t2 = 2.0f * (v - (-1.0f + 0.5f * g));
        r[g] = __expf(-t2 * t2);
    }
    o[0] = f2bf(f0)   | ((unsigned)f2bf(r[0]) << 16);
    o[1] = f2bf(r[1]) | ((unsigned)f2bf(r[2]) << 16);
    o[2] = f2bf(r[3]) | ((unsigned)f2bf(r[4]) << 16);
}

// A[M][768] bf16, k = i*6+f. Thread handles 4 features: reads float4, writes 48B.
__global__ __launch_bounds__(256) void prep_A(
        const float* __restrict__ x, const int* __restrict__ t_idx,
        const float* __restrict__ temb, uint4* __restrict__ A4)
{
    int tid = blockIdx.x * 256 + threadIdx.x;   // tid = m*32 + j
    int j = tid & 31;
    int m = tid >> 5;
    int h = (m >> 9) % Hh;                      // m = ((b*H+h)*N+n), N=512
    float4 v4;
    if (j < 30) v4 = *(const float4*)(x + m * 120 + j * 4);
    else        v4 = *(const float4*)(temb + t_idx[h] * 8 + (j - 30) * 4);
    unsigned o[12];
    feat6(v4.x, o + 0);
    feat6(v4.y, o + 3);
    feat6(v4.z, o + 6);
    feat6(v4.w, o + 9);
    uint4* dst = A4 + tid * 3;                  // 48 B contiguous, 16B-aligned
    dst[0] = make_uint4(o[0], o[1], o[2], o[3]);
    dst[1] = make_uint4(o[4], o[5], o[6], o[7]);
    dst[2] = make_uint4(o[8], o[9], o[10], o[11]);
}

// Pack [base_w | spline_w] -> bf16 Wt[O][768] (B^T layout, K-contiguous).
__global__ __launch_bounds__(256) void prep_W(
        const float* __restrict__ bw, const float* __restrict__ sw,
        unsigned int* __restrict__ Wt)
{
    int tid = blockIdx.x * 256 + threadIdx.x;   // tid = o*128 + i
    float f[6];
    f[0] = bw[tid];
    #pragma unroll
    for (int g = 0; g < 5; ++g) f[1 + g] = sw[tid * 5 + g];
    Wt[tid * 3 + 0] = f2bf(f[0]) | ((unsigned)f2bf(f[1]) << 16);
    Wt[tid * 3 + 1] = f2bf(f[2]) | ((unsigned)f2bf(f[3]) << 16);
    Wt[tid * 3 + 2] = f2bf(f[4]) | ((unsigned)f2bf(f[5]) << 16);
}

// C[M][512] = A @ Wt^T + bias. Block tile 128x256, 4 waves as 2x2,
// wave tile 64x128 (4x8 16x16x32 frags), BK=64, XOR-swizzled LDS chunks.
__global__ __launch_bounds__(256, 2) void gemm_kan(
        const __hip_bfloat16* __restrict__ A,
        const __hip_bfloat16* __restrict__ W,
        const float* __restrict__ bias,
        float* __restrict__ out)
{
    __shared__ char AsB[128 * 128];   // 128 rows x 128B (BK=64 bf16)
    __shared__ char BsB[256 * 128];   // 256 cols x 128B
    const int t    = threadIdx.x;
    const int wave = t >> 6;
    const int lane = t & 63;
    const int m_base = blockIdx.x * 128;
    const int n_base = blockIdx.y * 256;
    const int wm = (wave >> 1) * 64;      // wave row offset in block tile
    const int wn = (wave & 1) * 128;      // wave col offset
    const int ll = lane & 15;
    const int q4 = lane >> 4;

    f32x4 acc[4][8] = {};

    // ---- staging addresses (thread t stages row lr, phys slot s8 of 8x16B) ----
    const int lr = t >> 3;                // 0..31 local row within a 32-row issue
    const int s8 = t & 7;                 // phys 16B slot within 128B row
    const int cg = s8 ^ (lr & 7);         // global (logical) chunk this slot holds
    const __hip_bfloat16* ag = A + (long)(m_base + lr) * Ktot + cg * 8;
    const __hip_bfloat16* bg = W + (long)(n_base + lr) * Ktot + cg * 8;
    char* ldsA = AsB + wave * 1024;       // + q*4096 per 32-row issue
    char* ldsB = BsB + wave * 1024;

    // ---- fragment read offsets: phys chunk = (kk*4 + q4) ^ (ll&7) ----
    const int coff = ((q4 ^ (ll & 7)) * 16);        // kk=0; kk=1 is ^64
    const int aoff = (wm + ll) * 128 + coff;
    const int boff = (wn + ll) * 128 + coff;

    for (int kt = 0; kt < Ktot; kt += 64) {
        #pragma unroll
        for (int q = 0; q < 4; ++q)
            GLDS16(ag + kt + (long)q * 32 * Ktot, ldsA + q * 4096);
        #pragma unroll
        for (int q = 0; q < 8; ++q)
            GLDS16(bg + kt + (long)q * 32 * Ktot, ldsB + q * 4096);
        __syncthreads();                   // drain vmcnt -> LDS valid
        #pragma unroll
        for (int kk = 0; kk < 2; ++kk) {
            const int ao = kk ? (aoff ^ 64) : aoff;
            const int bo = kk ? (boff ^ 64) : boff;
            bf16x8 af[4], bf[8];
            #pragma unroll
            for (int mi = 0; mi < 4; ++mi) af[mi] = *(const bf16x8*)(AsB + ao + mi * 2048);
            #pragma unroll
            for (int ni = 0; ni < 8; ++ni) bf[ni] = *(const bf16x8*)(BsB + bo + ni * 2048);
            #pragma unroll
            for (int mi = 0; mi < 4; ++mi)
                #pragma unroll
                for (int ni = 0; ni < 8; ++ni)
                    acc[mi][ni] = __builtin_amdgcn_mfma_f32_16x16x32_bf16(
                        af[mi], bf[ni], acc[mi][ni], 0, 0, 0);
        }
        __syncthreads();                   // LDS reads done before next stage
    }

    // C/D layout: col = lane&15, row = (lane>>4)*4 + reg  [m89-verified]
    const int col0 = n_base + wn + ll;
    const int row0 = m_base + wm + q4 * 4;
    #pragma unroll
    for (int ni = 0; ni < 8; ++ni) {
        const int col = col0 + ni * 16;
        const float bv = bias[col];
        #pragma unroll
        for (int mi = 0; mi < 4; ++mi) {
            #pragma unroll
            for (int r = 0; r < 4; ++r) {
                out[(long)(row0 + mi * 16 + r) * Otot + col] = acc[mi][ni][r] + bv;
            }
        }
    }
}

extern "C" void kernel_launch(void* const* d_in, const int* in_sizes, int n_in,
                              void* d_out, int out_size, void* d_ws, size_t ws_size,
                              hipStream_t stream) {
    const float* x    = (const float*)d_in[0];
    const int*   tidx = (const int*)  d_in[1];
    const float* temb = (const float*)d_in[2];
    const float* bw   = (const float*)d_in[3];
    const float* bb   = (const float*)d_in[4];
    const float* sw   = (const float*)d_in[5];
    float* out = (float*)d_out;

    __hip_bfloat16* A  = (__hip_bfloat16*)d_ws;                         // 72 MiB
    __hip_bfloat16* Wt = (__hip_bfloat16*)((char*)d_ws + (size_t)Mtot * Ktot * 2);

    prep_A<<<Mtot * 32 / 256, 256, 0, stream>>>(x, tidx, temb, (uint4*)A);
    prep_W<<<Otot * 128 / 256, 256, 0, stream>>>(bw, sw, (unsigned int*)Wt);
    gemm_kan<<<dim3(Mtot / 128, Otot / 256), 256, 0, stream>>>(A, Wt, bb, out);
}